// Round 21
// baseline (739.377 us; speedup 1.0000x reference)
//
#include <hip/hip_runtime.h>

typedef unsigned short u16;
typedef unsigned int u32;
typedef unsigned long long u64;
typedef _Float16 f16;
typedef __attribute__((ext_vector_type(8))) __bf16 bf16x8;
typedef __attribute__((ext_vector_type(8))) _Float16 f16x8;
typedef __attribute__((ext_vector_type(4))) _Float16 f16x4;
typedef __attribute__((ext_vector_type(4))) float f32x4;

#define DEVI static __device__ __forceinline__

#define BB 32
#define SS 64
#define TT 63
#define VV 32000
#define EE 300
#define EP 320
#define HH 1024
#define H3 3072
#define MM 2016
#define MP 2048
#define NWG 192
#define NWG_TOT 256
#define NT 250

DEVI u16 f2bf(float f) {
  u32 x = __float_as_uint(f);
  u32 r = x + 0x7FFFu + ((x >> 16) & 1u);
  return (u16)(r >> 16);
}
DEVI float bf2f(u16 h) { return __uint_as_float(((u32)h) << 16); }
DEVI float sigm(float x) { return 1.0f / (1.0f + __expf(-x)); }
DEVI float tanh_(float x) { return 2.0f / (1.0f + __expf(-2.0f * x)) - 1.0f; }

DEVI void gl_lds16(const void* g, void* l) {
  __builtin_amdgcn_global_load_lds((const __attribute__((address_space(1))) void*)g,
                                   (__attribute__((address_space(3))) void*)l,
                                   16, 0, 0);
}

DEVI f32x4 mfma_bf16(bf16x8 a, bf16x8 b, f32x4 c) {
  return __builtin_amdgcn_mfma_f32_16x16x32_bf16(a, b, c, 0, 0, 0);
}
DEVI f32x4 mfma_f16(f16x8 a, f16x8 b, f32x4 c) {
  return __builtin_amdgcn_mfma_f32_16x16x32_f16(a, b, c, 0, 0, 0);
}

// Device-scope (IF$-coherent) h-state exchange, fragment-major layout:
// h buffer = [c4 = j>>2][b (0..31)][4 x f16]  (8B granule per (c4,b)).
DEVI f16x8 frag_ld(const f16* base, int kk, int kg, int brow) {
  const u64* q = (const u64*)base;
  int i0 = (kk * 8 + kg * 2) * 32 + brow;
  union { u64 u[2]; f16x8 v; } t;
  t.u[0] = __hip_atomic_load(q + i0, __ATOMIC_RELAXED, __HIP_MEMORY_SCOPE_AGENT);
  t.u[1] = __hip_atomic_load(q + i0 + 32, __ATOMIC_RELAXED, __HIP_MEMORY_SCOPE_AGENT);
  return t.v;
}
DEVI void ast32(u32* p, u32 v) {
  __hip_atomic_store(p, v, __ATOMIC_RELAXED, __HIP_MEMORY_SCOPE_AGENT);
}
DEVI u32 ald32(const u32* p) {
  return __hip_atomic_load(p, __ATOMIC_RELAXED, __HIP_MEMORY_SCOPE_AGENT);
}
// Writer slot for (col j0 even, batch b): bytes (j0>>2)*256 + b*8 + (j0&3)*2.
DEVI u32* frag_wslot(f16* base, int j0, int b) {
  return (u32*)((char*)base + ((j0 >> 2) * 256 + b * 8 + (j0 & 3) * 2));
}

// Distributed-flag grid barrier (R11-verified). Threads 0..NWG-1 poll.
DEVI void gbar(u32* flags, int wg, u32 target) {
  __syncthreads();
  if (threadIdx.x == 0) ast32(&flags[wg * 16], target);
  int ok;
  do {
    u32 v = (threadIdx.x < NWG) ? ald32(&flags[threadIdx.x * 16]) : target;
    ok = (v >= target);
  } while (__syncthreads_and(ok) == 0);
}

// ---------------- fused front-end: wi0 convert + x gather (one launch) ------

__global__ void prep_front(const float* __restrict__ Wi0, f16* __restrict__ wi0f,
                           const int* __restrict__ sent, const float* __restrict__ emb,
                           f16* __restrict__ xf) {
  if (blockIdx.x < 512) {
    int i = blockIdx.x * 256 + threadIdx.x;
    const int stride = 512 * 256;
    for (; i < H3 * EP; i += stride) {
      int r = i / EP, c = i % EP;
      wi0f[i] = (c < EE) ? (f16)Wi0[(size_t)r * EE + c] : (f16)0.0f;
    }
  } else {
    int i = (blockIdx.x - 512) * 256 + threadIdx.x;
    const int stride = 512 * 256;
    for (; i < MM * EP; i += stride) {
      int m = i / EP, c = i % EP;
      int t = m >> 5, b = m & 31;
      int tok = sent[b * SS + t];
      xf[i] = (c < EE) ? (f16)emb[(size_t)tok * EE + c] : (f16)0.0f;
    }
  }
}

// ---------------- GEMM (bf16): C[m][n] = A[m][:] . B[n][:] + bias[n] --------
// XSWZ: XCD-aware blockIdx swizzle (T1) — requires gridDim.x % 8 == 0.
// REMAP: also computes per-(row, ntile) partial softmax from registers, and
// uses NON-TEMPORAL logits stores (streaming output; avoids L2 write-allocate
// evicting the reused B panels — R17 FETCH showed 3x B over-fetch).
// __launch_bounds__(256,4): 4 blocks/CU for wave-level overlap (R20 verified).

template <bool REMAP, bool XSWZ>
__global__ __launch_bounds__(256, 4) void gemm_bt(const u16* __restrict__ Ah, int lda,
                                                  const u16* __restrict__ Bh,
                                                  const float* __restrict__ bias,
                                                  float* __restrict__ out, int out_stride,
                                                  int Ksteps, int Mtiles, int Mvalid,
                                                  float* __restrict__ pmg,
                                                  float* __restrict__ psg) {
  __shared__ u16 As[128 * 64];
  __shared__ u16 Bs[128 * 64];
  __shared__ float pm[128][2], ps[128][2];
  int bid = blockIdx.x;
  if (XSWZ) bid = (bid & 7) * (gridDim.x >> 3) + (bid >> 3);
  const int mtile = bid % Mtiles, ntile = bid / Mtiles;
  const int tid = threadIdx.x;
  const int lane = tid & 63, wave = tid >> 6;
  const int wrow = (wave & 1) * 64, wcol = (wave >> 1) * 64;
  const int l15 = lane & 15, kg = lane >> 4;

  f32x4 acc[4][4];
#pragma unroll
  for (int i = 0; i < 4; ++i)
#pragma unroll
    for (int j = 0; j < 4; ++j) {
      f32x4 z = {0.f, 0.f, 0.f, 0.f};
      acc[i][j] = z;
    }

  for (int ks = 0; ks < Ksteps; ++ks) {
    int k0 = ks * 64;
#pragma unroll
    for (int it = 0; it < 4; ++it) {
      int c = it * 256 + tid;
      int r = c >> 3, kc = (c & 7) * 8;
      gl_lds16(Ah + (size_t)(mtile * 128 + r) * lda + k0 + kc, &As[c * 8]);
      gl_lds16(Bh + (size_t)(ntile * 128 + r) * lda + k0 + kc, &Bs[c * 8]);
    }
    __syncthreads();
#pragma unroll
    for (int kk = 0; kk < 2; ++kk) {
      bf16x8 ah[4], bh[4];
#pragma unroll
      for (int i = 0; i < 4; ++i) {
        ah[i] = *(const bf16x8*)&As[(wrow + i * 16 + l15) * 64 + kk * 32 + kg * 8];
        bh[i] = *(const bf16x8*)&Bs[(wcol + i * 16 + l15) * 64 + kk * 32 + kg * 8];
      }
#pragma unroll
      for (int i = 0; i < 4; ++i)
#pragma unroll
        for (int j = 0; j < 4; ++j) acc[i][j] = mfma_bf16(ah[i], bh[j], acc[i][j]);
    }
    __syncthreads();
  }

  float bv4[4];
#pragma unroll
  for (int j = 0; j < 4; ++j) bv4[j] = bias[ntile * 128 + wcol + j * 16 + l15];

  const int r0 = kg * 4;
#pragma unroll
  for (int i = 0; i < 4; ++i) {
    int mbase = mtile * 128 + wrow + i * 16 + r0;
#pragma unroll
    for (int j = 0; j < 4; ++j) {
      int n = ntile * 128 + wcol + j * 16 + l15;
#pragma unroll
      for (int reg = 0; reg < 4; ++reg) {
        int m = mbase + reg;
        if (m < Mvalid) {
          float v = acc[i][j][reg] + bv4[j];
          if (REMAP) {
            int b = m & 31, s = m >> 5;
            size_t oidx = ((size_t)(b * TT + s)) * VV + n;
            __builtin_nontemporal_store(v, &out[oidx]);
          } else {
            out[(size_t)m * out_stride + n] = v;
          }
        }
      }
    }
  }

  if constexpr (REMAP) {
#pragma unroll
    for (int i = 0; i < 4; ++i) {
#pragma unroll
      for (int reg = 0; reg < 4; ++reg) {
        float v0 = acc[i][0][reg] + bv4[0];
        float v1 = acc[i][1][reg] + bv4[1];
        float v2 = acc[i][2][reg] + bv4[2];
        float v3 = acc[i][3][reg] + bv4[3];
        float rm = fmaxf(fmaxf(v0, v1), fmaxf(v2, v3));
#pragma unroll
        for (int off = 1; off < 16; off <<= 1) rm = fmaxf(rm, __shfl_xor(rm, off));
        float sm = __expf(v0 - rm) + __expf(v1 - rm) + __expf(v2 - rm) +
                   __expf(v3 - rm);
#pragma unroll
        for (int off = 1; off < 16; off <<= 1) sm += __shfl_xor(sm, off);
        if (l15 == 0) {
          int r128 = wrow + i * 16 + kg * 4 + reg;
          pm[r128][wcol >> 6] = rm;
          ps[r128][wcol >> 6] = sm;
        }
      }
    }
    __syncthreads();
    if (tid < 128) {
      int m = mtile * 128 + tid;
      if (m < Mvalid) {
        float m0 = pm[tid][0], m1 = pm[tid][1];
        float s0 = ps[tid][0], s1 = ps[tid][1];
        float mn = fmaxf(m0, m1);
        float ss = s0 * __expf(m0 - mn) + s1 * __expf(m1 - mn);
        int b = m & 31, s = m >> 5;
        size_t rr = (size_t)(b * TT + s);
        pmg[(size_t)ntile * MM + rr] = mn;
        psg[(size_t)ntile * MM + rr] = ss;
      }
    }
  }
}

// f16 variant (same verified structure) for the gx0 input GEMM.
__global__ __launch_bounds__(256) void gemm_bt_f16(const f16* __restrict__ A, int lda,
                                                   const f16* __restrict__ B,
                                                   const float* __restrict__ bias,
                                                   float* __restrict__ out, int out_stride,
                                                   int Ksteps, int Mtiles, int Mvalid) {
  __shared__ f16 As[128 * 64];
  __shared__ f16 Bs[128 * 64];
  const int bid = blockIdx.x;
  const int mtile = bid % Mtiles, ntile = bid / Mtiles;
  const int tid = threadIdx.x;
  const int lane = tid & 63, wave = tid >> 6;
  const int wrow = (wave & 1) * 64, wcol = (wave >> 1) * 64;
  const int l15 = lane & 15, kg = lane >> 4;

  f32x4 acc[4][4];
#pragma unroll
  for (int i = 0; i < 4; ++i)
#pragma unroll
    for (int j = 0; j < 4; ++j) {
      f32x4 z = {0.f, 0.f, 0.f, 0.f};
      acc[i][j] = z;
    }

  for (int ks = 0; ks < Ksteps; ++ks) {
    int k0 = ks * 64;
#pragma unroll
    for (int it = 0; it < 4; ++it) {
      int c = it * 256 + tid;
      int r = c >> 3, kc = (c & 7) * 8;
      gl_lds16(A + (size_t)(mtile * 128 + r) * lda + k0 + kc, &As[c * 8]);
      gl_lds16(B + (size_t)(ntile * 128 + r) * lda + k0 + kc, &Bs[c * 8]);
    }
    __syncthreads();
#pragma unroll
    for (int kk = 0; kk < 2; ++kk) {
      f16x8 a[4], b[4];
#pragma unroll
      for (int i = 0; i < 4; ++i) {
        a[i] = *(const f16x8*)&As[(wrow + i * 16 + l15) * 64 + kk * 32 + kg * 8];
        b[i] = *(const f16x8*)&Bs[(wcol + i * 16 + l15) * 64 + kk * 32 + kg * 8];
      }
#pragma unroll
      for (int i = 0; i < 4; ++i)
#pragma unroll
        for (int j = 0; j < 4; ++j) acc[i][j] = mfma_f16(a[i], b[j], acc[i][j]);
    }
    __syncthreads();
  }

  const int r0 = kg * 4;
#pragma unroll
  for (int i = 0; i < 4; ++i) {
    int mbase = mtile * 128 + wrow + i * 16 + r0;
#pragma unroll
    for (int j = 0; j < 4; ++j) {
      int n = ntile * 128 + wcol + j * 16 + l15;
      float bv = bias[n];
#pragma unroll
      for (int reg = 0; reg < 4; ++reg) {
        int m = mbase + reg;
        if (m < Mvalid) {
          out[(size_t)m * out_stride + n] = acc[i][j][reg] + bv;
        }
      }
    }
  }
}

// ---------------- recurrence (256 WGs x 1024 thr, split-K 4-way) ------------
// WGs 0..191: rec (verified split-K template). WGs 192..255: Wout cvt.
// Weight staging converts fp32->f16 inline.

struct RecArgs {
  const float *wh0, *wi1, *wh1;  // fp32 weights (converted in prologue)
  const float *gx0, *bh0, *bi1, *bh1;
  f16 *h0x, *h1x;  // fragment-major exchange buffers, [2][BB*HH] f16
  u16 *hs;
  u32 *bar;  // NWG flag lines, 64B each
  const float *wout;  // Wout fp32 (input)
  u16 *woutb;         // Wout bf16 (output, converted by WGs >= NWG)
};

__global__ __launch_bounds__(1024, 1) void rec_kernel(RecArgs ra) {
  __shared__ f16 wlds[48 * 1024];
  __shared__ float gh[4 * 48 * 33];
  const int tid = threadIdx.x;
  const int wg = blockIdx.x;

  if (wg >= NWG) {
    // ---- Wout converter WGs (idle CUs during rec) ----
    int i = (wg - NWG) * 1024 + tid;
    const int stride = (NWG_TOT - NWG) * 1024;
    for (; i < VV * HH / 4; i += stride) {
      float4 v = ((const float4*)ra.wout)[i];
      ushort4 o;
      o.x = f2bf(v.x); o.y = f2bf(v.y); o.z = f2bf(v.z); o.w = f2bf(v.w);
      ((ushort4*)ra.woutb)[i] = o;
    }
    return;
  }

  const int lane = tid & 63, wave = tid >> 6;
  const bool isL0 = wg < 64;
  const int Jbase = isL0 ? (wg * 16) : ((wg - 64) * 8);
  const int l15 = lane & 15;
  const int kg = lane >> 4;
  const int swz = (l15 & 7) << 4;
  const int kh = wave >> 2;   // K quarter 0..3
  const int khk = kh * 8;     // kk base
  float* ghk = gh + kh * (48 * 33);
  char* wb = (char*)wlds;

  // ---- prologue: stage this WG's weight slice into LDS, converting
  // fp32 -> f16 inline (same verified row mapping and XOR swizzle) ----
#pragma unroll
  for (int it = 0; it < 6; ++it) {
    int q = it * 1024 + tid;  // 0..6143
    int r = q >> 7;           // LDS row 0..47
    int c16 = q & 127;        // 16B f16 chunk (= 8 elems) within row
    const float* gp;
    if (isL0) {
      int gate = r >> 4, colr = r & 15;
      gp = ra.wh0 + ((size_t)(gate * HH + Jbase + colr)) * HH + c16 * 8;
    } else {
      int tile = r >> 3, colr = r & 7;
      int msrc = tile / 3, gate = tile - msrc * 3;
      const float* W = msrc ? ra.wh1 : ra.wi1;
      gp = W + ((size_t)(gate * HH + Jbase + colr)) * HH + c16 * 8;
    }
    float4 lo = ((const float4*)gp)[0];
    float4 hi = ((const float4*)gp)[1];
    f16x8 v = {(f16)lo.x, (f16)lo.y, (f16)lo.z, (f16)lo.w,
               (f16)hi.x, (f16)hi.y, (f16)hi.z, (f16)hi.w};
    int byte = r * 2048 + ((c16 * 16) ^ ((r & 7) << 4));
    *(f16x8*)(wb + byte) = v;
  }

  // ---- per-thread EW state (1 column each): biases + h_prev in registers --
  const int ewb = tid & 31, ewj = tid >> 5;  // L0: tid<512 (ewj 0..15); L1: tid<256
  float hprev = 0.f;
  float pb0r = 0.f, pb0z = 0.f, pb0n = 0.f;
  float pbrz_r = 0.f, pbrz_z = 0.f, pbn_i = 0.f, pbn_h = 0.f;
  if (isL0 && tid < 512) {
    int gj = Jbase + ewj;
    pb0r = ra.bh0[gj];
    pb0z = ra.bh0[HH + gj];
    pb0n = ra.bh0[2 * HH + gj];
  } else if (!isL0 && tid < 256) {
    int gj = Jbase + ewj;
    pbrz_r = ra.bi1[gj] + ra.bh1[gj];
    pbrz_z = ra.bi1[HH + gj] + ra.bh1[HH + gj];
    pbn_i = ra.bi1[2 * HH + gj];
    pbn_h = ra.bh1[2 * HH + gj];
  }
  __syncthreads();

  for (int p = 0; p < 64; ++p) {
    const int pb = p & 1, qb = (p + 1) & 1;
    if (isL0) {
      if (p < TT) {
        // prefetch gx for this thread's EW column
        float gr = 0.f, gz = 0.f, gn = 0.f;
        if (tid < 512) {
          const float* gxb = ra.gx0 + ((size_t)p * BB + ewb) * H3;
          int gj = Jbase + ewj;
          gr = gxb[gj];
          gz = gxb[HH + gj];
          gn = gxb[2 * HH + gj];
        }
        const int rt = (wave >> 1) & 1, tt = wave & 1;
        const f16* h0base = ra.h0x + (size_t)qb * (BB * HH);
        const int brow = rt * 16 + l15;
        f32x4 z = {0.f, 0.f, 0.f, 0.f};
        if (tt == 0) {
          f32x4 acc0 = z, acc1 = z;
#pragma unroll 4
          for (int ki = 0; ki < 8; ++ki) {
            int kk = khk + ki;
            f16x8 a = frag_ld(h0base, kk, kg, brow);
            int inner = (kk * 64 + kg * 16) ^ swz;
            f16x8 b0 = *(const f16x8*)(wb + (0 * 16 + l15) * 2048 + inner);
            f16x8 b1 = *(const f16x8*)(wb + (1 * 16 + l15) * 2048 + inner);
            acc0 = mfma_f16(a, b0, acc0);
            acc1 = mfma_f16(a, b1, acc1);
          }
#pragma unroll
          for (int r = 0; r < 4; ++r) {
            ghk[(l15)*33 + rt * 16 + kg * 4 + r] = acc0[r];
            ghk[(16 + l15) * 33 + rt * 16 + kg * 4 + r] = acc1[r];
          }
        } else {
          f32x4 acc2 = z;
#pragma unroll 4
          for (int ki = 0; ki < 8; ++ki) {
            int kk = khk + ki;
            f16x8 a = frag_ld(h0base, kk, kg, brow);
            int inner = (kk * 64 + kg * 16) ^ swz;
            f16x8 b2 = *(const f16x8*)(wb + (2 * 16 + l15) * 2048 + inner);
            acc2 = mfma_f16(a, b2, acc2);
          }
#pragma unroll
          for (int r = 0; r < 4; ++r)
            ghk[(32 + l15) * 33 + rt * 16 + kg * 4 + r] = acc2[r];
        }
        __syncthreads();
        // elementwise (1 col/thread, tid<512); pack (j,j+1) via lanes L,L+32
        if (tid < 512) {
          f16* hxc = ra.h0x + (size_t)pb * (BB * HH);
          float rh = pb0r, zh = pb0z, nh = pb0n;
#pragma unroll
          for (int g = 0; g < 4; ++g) {
            rh += gh[g * (48 * 33) + (ewj)*33 + ewb];
            zh += gh[g * (48 * 33) + (16 + ewj) * 33 + ewb];
            nh += gh[g * (48 * 33) + (32 + ewj) * 33 + ewb];
          }
          float r = sigm(gr + rh);
          float zz = sigm(gz + zh);
          float n = tanh_(gn + r * nh);
          float hn = (1.f - zz) * n + zz * hprev;
          hprev = hn;
          float other = __shfl_xor(hn, 32);
          if ((lane & 32) == 0) {
            union { f16 h[2]; u32 u; } pk;
            pk.h[0] = (f16)hn;
            pk.h[1] = (f16)other;
            ast32(frag_wslot(hxc, Jbase + ewj, ewb), pk.u);
          }
        }
      } else {
        __syncthreads();
      }
    } else {
      if (p >= 1) {
        const int rt = (wave >> 1) & 1, src = wave & 1;
        const f16* hbase = (src ? ra.h1x : ra.h0x) + (size_t)qb * (BB * HH);
        const int brow = rt * 16 + l15;
        const int rowb = src * 24 + (l15 & 7);
        f32x4 z = {0.f, 0.f, 0.f, 0.f};
        f32x4 acc0 = z, acc1 = z, acc2 = z;
#pragma unroll 4
        for (int ki = 0; ki < 8; ++ki) {
          int kk = khk + ki;
          f16x8 a = frag_ld(hbase, kk, kg, brow);
          int inner = (kk * 64 + kg * 16) ^ swz;
          f16x8 b0 = *(const f16x8*)(wb + (rowb + 0) * 2048 + inner);
          f16x8 b1 = *(const f16x8*)(wb + (rowb + 8) * 2048 + inner);
          f16x8 b2 = *(const f16x8*)(wb + (rowb + 16) * 2048 + inner);
          acc0 = mfma_f16(a, b0, acc0);
          acc1 = mfma_f16(a, b1, acc1);
          acc2 = mfma_f16(a, b2, acc2);
        }
        if (l15 < 8) {
          f32x4 accs[3] = {acc0, acc1, acc2};
#pragma unroll
          for (int g = 0; g < 3; ++g) {
            int cl = (src * 3 + g) * 8 + l15;
#pragma unroll
            for (int r = 0; r < 4; ++r)
              ghk[cl * 33 + rt * 16 + kg * 4 + r] = accs[g][r];
          }
        }
        __syncthreads();
        if (tid < 256) {
          f16* hxc = ra.h1x + (size_t)pb * (BB * HH);
          float gir = 0.f, giz = 0.f, gin = 0.f, ghr = 0.f, ghz = 0.f, ghn = 0.f;
#pragma unroll
          for (int g = 0; g < 4; ++g) {
            const float* gg = gh + g * (48 * 33);
            gir += gg[(ewj)*33 + ewb];
            giz += gg[(8 + ewj) * 33 + ewb];
            gin += gg[(16 + ewj) * 33 + ewb];
            ghr += gg[(24 + ewj) * 33 + ewb];
            ghz += gg[(32 + ewj) * 33 + ewb];
            ghn += gg[(40 + ewj) * 33 + ewb];
          }
          float r = sigm(gir + ghr + pbrz_r);
          float zz = sigm(giz + ghz + pbrz_z);
          float n = tanh_(gin + pbn_i + r * (ghn + pbn_h));
          float hn = (1.f - zz) * n + zz * hprev;
          hprev = hn;
          float other = __shfl_xor(hn, 32);
          if ((lane & 32) == 0) {
            union { f16 h[2]; u32 u; } pk;
            pk.h[0] = (f16)hn;
            pk.h[1] = (f16)other;
            ast32(frag_wslot(hxc, Jbase + ewj, ewb), pk.u);
            union { u16 h[2]; u32 u; } pb2;
            pb2.h[0] = f2bf(hn);
            pb2.h[1] = f2bf(other);
            *(u32*)&ra.hs[((size_t)(p - 1) * BB + ewb) * HH + Jbase + ewj] = pb2.u;
          }
        }
      } else {
        __syncthreads();
      }
    }
    if (p < 63) gbar(ra.bar, wg, (u32)(p + 1));
  }
}

// ---------------- final row reduction (over NT partials) + loss -------------

__global__ __launch_bounds__(256) void rowred2_kernel(const float* __restrict__ pmg,
                                                      const float* __restrict__ psg,
                                                      const float* __restrict__ logits,
                                                      const int* __restrict__ sent,
                                                      const int* __restrict__ length,
                                                      float* __restrict__ tok) {
  __shared__ float redm[4], reds[4];
  const int row = blockIdx.x;  // rr = b*63 + s
  const int b = row / TT, s = row % TT;
  const int tid = threadIdx.x;
  const int lane = tid & 63, wave = tid >> 6;

  float m = -1e30f, sum = 0.f;
  if (tid < NT) {
    m = pmg[(size_t)tid * MM + row];
    sum = psg[(size_t)tid * MM + row];
  }
  for (int off = 1; off < 64; off <<= 1) {
    float mo = __shfl_xor(m, off);
    float so = __shfl_xor(sum, off);
    float mn = fmaxf(m, mo);
    sum = sum * __expf(m - mn) + so * __expf(mo - mn);
    m = mn;
  }
  if (lane == 0) {
    redm[wave] = m;
    reds[wave] = sum;
  }
  __syncthreads();
  if (tid == 0) {
    float M = redm[0], S = reds[0];
#pragma unroll
    for (int w = 1; w < 4; ++w) {
      float mo = redm[w], so = reds[w];
      float mn = fmaxf(M, mo);
      S = S * __expf(M - mn) + so * __expf(mo - mn);
      M = mn;
    }
    float lse = M + __logf(S);
    int tgt = sent[b * SS + s + 1];
    float tl = logits[(size_t)row * VV + tgt] - lse;
    if (s >= length[b] - 1) tl = 0.f;
    tok[row] = tl;
  }
}

__global__ void loss_kernel(const float* __restrict__ tok, const int* __restrict__ length,
                            float* __restrict__ out0) {
  int lane = threadIdx.x;
  float v = 0.f;
  if (lane < BB) {
    float s = 0.f;
    for (int t = 0; t < TT; ++t) s += tok[lane * TT + t];
    float ln = (float)(length[lane] - 1);
    v = -s / ln;
  }
  v += __shfl_down(v, 16);
  v += __shfl_down(v, 8);
  v += __shfl_down(v, 4);
  v += __shfl_down(v, 2);
  v += __shfl_down(v, 1);
  if (lane == 0) out0[0] = v / (float)BB;
}

// ---------------- host ----------------

extern "C" void kernel_launch(void* const* d_in, const int* in_sizes, int n_in,
                              void* d_out, int out_size, void* d_ws, size_t ws_size,
                              hipStream_t stream) {
  const int* sent = (const int*)d_in[0];
  const int* length = (const int*)d_in[1];
  const float* emb = (const float*)d_in[2];
  const float* Wi0 = (const float*)d_in[3];
  const float* Wh0 = (const float*)d_in[4];
  const float* bi0 = (const float*)d_in[5];
  const float* bh0 = (const float*)d_in[6];
  const float* Wi1 = (const float*)d_in[7];
  const float* Wh1 = (const float*)d_in[8];
  const float* bi1 = (const float*)d_in[9];
  const float* bh1 = (const float*)d_in[10];
  const float* Wout = (const float*)d_in[11];
  const float* bout = (const float*)d_in[12];
  float* out = (float*)d_out;

  char* ws = (char*)d_ws;
  size_t off = 0;
  auto alloc = [&](size_t b) {
    char* p = ws + off;
    off = (off + b + 255) & ~(size_t)255;
    return p;
  };
  f16* wi0f = (f16*)alloc((size_t)H3 * EP * 2);
  f16* xf = (f16*)alloc((size_t)MP * EP * 2);
  float* gx0 = (float*)alloc((size_t)MM * H3 * 4);
  u16* woutb = (u16*)alloc((size_t)VV * HH * 2);  // converted inside rec
  u16* hs = (u16*)alloc((size_t)MP * HH * 2);
  f16* h0x = (f16*)alloc((size_t)2 * BB * HH * 2);
  f16* h1x = (f16*)alloc((size_t)2 * BB * HH * 2);
  float* tok = (float*)alloc((size_t)MM * 4);
  u32* bar = (u32*)alloc((size_t)NWG * 16 * 4);
  float* pmg = (float*)alloc((size_t)MM * NT * 4);
  float* psg = (float*)alloc((size_t)MM * NT * 4);

  hipMemsetAsync(h0x, 0, (size_t)2 * BB * HH * 2, stream);
  hipMemsetAsync(h1x, 0, (size_t)2 * BB * HH * 2, stream);
  hipMemsetAsync(hs, 0, (size_t)MP * HH * 2, stream);
  hipMemsetAsync(bar, 0, (size_t)NWG * 16 * 4, stream);
  hipMemsetAsync(xf + (size_t)MM * EP, 0, (size_t)(MP - MM) * EP * 2, stream);

  prep_front<<<1024, 256, 0, stream>>>(Wi0, wi0f, sent, emb, xf);

  gemm_bt_f16<<<16 * 24, 256, 0, stream>>>(xf, EP, wi0f, bi0, gx0, H3, 5, 16, MM);

  RecArgs ra{Wh0, Wi1, Wh1, gx0, bh0, bi1, bh1, h0x, h1x, hs, bar, Wout, woutb};
  void* kargs[] = {(void*)&ra};
  hipLaunchCooperativeKernel((void*)rec_kernel, dim3(NWG_TOT), dim3(1024), kargs, 0,
                             stream);

  gemm_bt<true, true><<<16 * 250, 256, 0, stream>>>(hs, HH, woutb, bout, out + 1, VV, 16,
                                                    16, MM, pmg, psg);

  rowred2_kernel<<<MM, 256, 0, stream>>>(pmg, psg, out + 1, sent, length, tok);
  loss_kernel<<<1, 64, 0, stream>>>(tok, length, out);
}

// Round 22
// 637.991 us; speedup vs baseline: 1.1589x; 1.1589x over previous
//
#include <hip/hip_runtime.h>

typedef unsigned short u16;
typedef unsigned int u32;
typedef unsigned long long u64;
typedef _Float16 f16;
typedef __attribute__((ext_vector_type(8))) __bf16 bf16x8;
typedef __attribute__((ext_vector_type(8))) _Float16 f16x8;
typedef __attribute__((ext_vector_type(4))) _Float16 f16x4;
typedef __attribute__((ext_vector_type(4))) float f32x4;

#define DEVI static __device__ __forceinline__

#define BB 32
#define SS 64
#define TT 63
#define VV 32000
#define EE 300
#define EP 320
#define HH 1024
#define H3 3072
#define MM 2016
#define MP 2048
#define NWG 192
#define NWG_TOT 256
#define NT 250

DEVI u16 f2bf(float f) {
  u32 x = __float_as_uint(f);
  u32 r = x + 0x7FFFu + ((x >> 16) & 1u);
  return (u16)(r >> 16);
}
DEVI float bf2f(u16 h) { return __uint_as_float(((u32)h) << 16); }
DEVI float sigm(float x) { return 1.0f / (1.0f + __expf(-x)); }
DEVI float tanh_(float x) { return 2.0f / (1.0f + __expf(-2.0f * x)) - 1.0f; }

DEVI void gl_lds16(const void* g, void* l) {
  __builtin_amdgcn_global_load_lds((const __attribute__((address_space(1))) void*)g,
                                   (__attribute__((address_space(3))) void*)l,
                                   16, 0, 0);
}

DEVI f32x4 mfma_bf16(bf16x8 a, bf16x8 b, f32x4 c) {
  return __builtin_amdgcn_mfma_f32_16x16x32_bf16(a, b, c, 0, 0, 0);
}
DEVI f32x4 mfma_f16(f16x8 a, f16x8 b, f32x4 c) {
  return __builtin_amdgcn_mfma_f32_16x16x32_f16(a, b, c, 0, 0, 0);
}

// Device-scope (IF$-coherent) h-state exchange, fragment-major layout:
// h buffer = [c4 = j>>2][b (0..31)][4 x f16]  (8B granule per (c4,b)).
DEVI f16x8 frag_ld(const f16* base, int kk, int kg, int brow) {
  const u64* q = (const u64*)base;
  int i0 = (kk * 8 + kg * 2) * 32 + brow;
  union { u64 u[2]; f16x8 v; } t;
  t.u[0] = __hip_atomic_load(q + i0, __ATOMIC_RELAXED, __HIP_MEMORY_SCOPE_AGENT);
  t.u[1] = __hip_atomic_load(q + i0 + 32, __ATOMIC_RELAXED, __HIP_MEMORY_SCOPE_AGENT);
  return t.v;
}
DEVI void ast32(u32* p, u32 v) {
  __hip_atomic_store(p, v, __ATOMIC_RELAXED, __HIP_MEMORY_SCOPE_AGENT);
}
DEVI u32 ald32(const u32* p) {
  return __hip_atomic_load(p, __ATOMIC_RELAXED, __HIP_MEMORY_SCOPE_AGENT);
}
// Writer slot for (col j0 even, batch b): bytes (j0>>2)*256 + b*8 + (j0&3)*2.
DEVI u32* frag_wslot(f16* base, int j0, int b) {
  return (u32*)((char*)base + ((j0 >> 2) * 256 + b * 8 + (j0 & 3) * 2));
}

// Distributed-flag grid barrier (R11-verified). Threads 0..NWG-1 poll.
DEVI void gbar(u32* flags, int wg, u32 target) {
  __syncthreads();
  if (threadIdx.x == 0) ast32(&flags[wg * 16], target);
  int ok;
  do {
    u32 v = (threadIdx.x < NWG) ? ald32(&flags[threadIdx.x * 16]) : target;
    ok = (v >= target);
  } while (__syncthreads_and(ok) == 0);
}

// ---------------- fused front-end: wi0 convert + x gather (one launch) ------

__global__ void prep_front(const float* __restrict__ Wi0, f16* __restrict__ wi0f,
                           const int* __restrict__ sent, const float* __restrict__ emb,
                           f16* __restrict__ xf) {
  if (blockIdx.x < 512) {
    int i = blockIdx.x * 256 + threadIdx.x;
    const int stride = 512 * 256;
    for (; i < H3 * EP; i += stride) {
      int r = i / EP, c = i % EP;
      wi0f[i] = (c < EE) ? (f16)Wi0[(size_t)r * EE + c] : (f16)0.0f;
    }
  } else {
    int i = (blockIdx.x - 512) * 256 + threadIdx.x;
    const int stride = 512 * 256;
    for (; i < MM * EP; i += stride) {
      int m = i / EP, c = i % EP;
      int t = m >> 5, b = m & 31;
      int tok = sent[b * SS + t];
      xf[i] = (c < EE) ? (f16)emb[(size_t)tok * EE + c] : (f16)0.0f;
    }
  }
}

// ---------------- GEMM (bf16): C[m][n] = A[m][:] . B[n][:] + bias[n] --------
// XSWZ: XCD-aware blockIdx swizzle (T1) — requires gridDim.x % 8 == 0.
// REMAP additionally computes per-(row, ntile) partial softmax (max, sumexp)
// from the in-register acc tile (two-pass, bias cached, coalesced partials).
// __launch_bounds__(256,4): 4 blocks/CU (35 KB LDS each) to raise wave-level
// overlap across the per-K-step barrier drain (m114 mechanism; R20 verified).

template <bool REMAP, bool XSWZ>
__global__ __launch_bounds__(256, 4) void gemm_bt(const u16* __restrict__ Ah, int lda,
                                                  const u16* __restrict__ Bh,
                                                  const float* __restrict__ bias,
                                                  float* __restrict__ out, int out_stride,
                                                  int Ksteps, int Mtiles, int Mvalid,
                                                  float* __restrict__ pmg,
                                                  float* __restrict__ psg) {
  __shared__ u16 As[128 * 64];
  __shared__ u16 Bs[128 * 64];
  __shared__ float pm[128][2], ps[128][2];
  int bid = blockIdx.x;
  if (XSWZ) bid = (bid & 7) * (gridDim.x >> 3) + (bid >> 3);
  const int mtile = bid % Mtiles, ntile = bid / Mtiles;
  const int tid = threadIdx.x;
  const int lane = tid & 63, wave = tid >> 6;
  const int wrow = (wave & 1) * 64, wcol = (wave >> 1) * 64;
  const int l15 = lane & 15, kg = lane >> 4;

  f32x4 acc[4][4];
#pragma unroll
  for (int i = 0; i < 4; ++i)
#pragma unroll
    for (int j = 0; j < 4; ++j) {
      f32x4 z = {0.f, 0.f, 0.f, 0.f};
      acc[i][j] = z;
    }

  for (int ks = 0; ks < Ksteps; ++ks) {
    int k0 = ks * 64;
#pragma unroll
    for (int it = 0; it < 4; ++it) {
      int c = it * 256 + tid;
      int r = c >> 3, kc = (c & 7) * 8;
      gl_lds16(Ah + (size_t)(mtile * 128 + r) * lda + k0 + kc, &As[c * 8]);
      gl_lds16(Bh + (size_t)(ntile * 128 + r) * lda + k0 + kc, &Bs[c * 8]);
    }
    __syncthreads();
#pragma unroll
    for (int kk = 0; kk < 2; ++kk) {
      bf16x8 ah[4], bh[4];
#pragma unroll
      for (int i = 0; i < 4; ++i) {
        ah[i] = *(const bf16x8*)&As[(wrow + i * 16 + l15) * 64 + kk * 32 + kg * 8];
        bh[i] = *(const bf16x8*)&Bs[(wcol + i * 16 + l15) * 64 + kk * 32 + kg * 8];
      }
#pragma unroll
      for (int i = 0; i < 4; ++i)
#pragma unroll
        for (int j = 0; j < 4; ++j) acc[i][j] = mfma_bf16(ah[i], bh[j], acc[i][j]);
    }
    __syncthreads();
  }

  float bv4[4];
#pragma unroll
  for (int j = 0; j < 4; ++j) bv4[j] = bias[ntile * 128 + wcol + j * 16 + l15];

  const int r0 = kg * 4;
#pragma unroll
  for (int i = 0; i < 4; ++i) {
    int mbase = mtile * 128 + wrow + i * 16 + r0;
#pragma unroll
    for (int j = 0; j < 4; ++j) {
      int n = ntile * 128 + wcol + j * 16 + l15;
#pragma unroll
      for (int reg = 0; reg < 4; ++reg) {
        int m = mbase + reg;
        if (m < Mvalid) {
          float v = acc[i][j][reg] + bv4[j];
          size_t oidx;
          if (REMAP) {
            int b = m & 31, s = m >> 5;
            oidx = ((size_t)(b * TT + s)) * VV + n;
          } else {
            oidx = (size_t)m * out_stride + n;
          }
          out[oidx] = v;
        }
      }
    }
  }

  if constexpr (REMAP) {
#pragma unroll
    for (int i = 0; i < 4; ++i) {
#pragma unroll
      for (int reg = 0; reg < 4; ++reg) {
        float v0 = acc[i][0][reg] + bv4[0];
        float v1 = acc[i][1][reg] + bv4[1];
        float v2 = acc[i][2][reg] + bv4[2];
        float v3 = acc[i][3][reg] + bv4[3];
        float rm = fmaxf(fmaxf(v0, v1), fmaxf(v2, v3));
#pragma unroll
        for (int off = 1; off < 16; off <<= 1) rm = fmaxf(rm, __shfl_xor(rm, off));
        float sm = __expf(v0 - rm) + __expf(v1 - rm) + __expf(v2 - rm) +
                   __expf(v3 - rm);
#pragma unroll
        for (int off = 1; off < 16; off <<= 1) sm += __shfl_xor(sm, off);
        if (l15 == 0) {
          int r128 = wrow + i * 16 + kg * 4 + reg;
          pm[r128][wcol >> 6] = rm;
          ps[r128][wcol >> 6] = sm;
        }
      }
    }
    __syncthreads();
    if (tid < 128) {
      int m = mtile * 128 + tid;
      if (m < Mvalid) {
        float m0 = pm[tid][0], m1 = pm[tid][1];
        float s0 = ps[tid][0], s1 = ps[tid][1];
        float mn = fmaxf(m0, m1);
        float ss = s0 * __expf(m0 - mn) + s1 * __expf(m1 - mn);
        int b = m & 31, s = m >> 5;
        size_t rr = (size_t)(b * TT + s);
        pmg[(size_t)ntile * MM + rr] = mn;
        psg[(size_t)ntile * MM + rr] = ss;
      }
    }
  }
}

// f16 variant (same verified structure) for the gx0 input GEMM.
__global__ __launch_bounds__(256) void gemm_bt_f16(const f16* __restrict__ A, int lda,
                                                   const f16* __restrict__ B,
                                                   const float* __restrict__ bias,
                                                   float* __restrict__ out, int out_stride,
                                                   int Ksteps, int Mtiles, int Mvalid) {
  __shared__ f16 As[128 * 64];
  __shared__ f16 Bs[128 * 64];
  const int bid = blockIdx.x;
  const int mtile = bid % Mtiles, ntile = bid / Mtiles;
  const int tid = threadIdx.x;
  const int lane = tid & 63, wave = tid >> 6;
  const int wrow = (wave & 1) * 64, wcol = (wave >> 1) * 64;
  const int l15 = lane & 15, kg = lane >> 4;

  f32x4 acc[4][4];
#pragma unroll
  for (int i = 0; i < 4; ++i)
#pragma unroll
    for (int j = 0; j < 4; ++j) {
      f32x4 z = {0.f, 0.f, 0.f, 0.f};
      acc[i][j] = z;
    }

  for (int ks = 0; ks < Ksteps; ++ks) {
    int k0 = ks * 64;
#pragma unroll
    for (int it = 0; it < 4; ++it) {
      int c = it * 256 + tid;
      int r = c >> 3, kc = (c & 7) * 8;
      gl_lds16(A + (size_t)(mtile * 128 + r) * lda + k0 + kc, &As[c * 8]);
      gl_lds16(B + (size_t)(ntile * 128 + r) * lda + k0 + kc, &Bs[c * 8]);
    }
    __syncthreads();
#pragma unroll
    for (int kk = 0; kk < 2; ++kk) {
      f16x8 a[4], b[4];
#pragma unroll
      for (int i = 0; i < 4; ++i) {
        a[i] = *(const f16x8*)&As[(wrow + i * 16 + l15) * 64 + kk * 32 + kg * 8];
        b[i] = *(const f16x8*)&Bs[(wcol + i * 16 + l15) * 64 + kk * 32 + kg * 8];
      }
#pragma unroll
      for (int i = 0; i < 4; ++i)
#pragma unroll
        for (int j = 0; j < 4; ++j) acc[i][j] = mfma_f16(a[i], b[j], acc[i][j]);
    }
    __syncthreads();
  }

  const int r0 = kg * 4;
#pragma unroll
  for (int i = 0; i < 4; ++i) {
    int mbase = mtile * 128 + wrow + i * 16 + r0;
#pragma unroll
    for (int j = 0; j < 4; ++j) {
      int n = ntile * 128 + wcol + j * 16 + l15;
      float bv = bias[n];
#pragma unroll
      for (int reg = 0; reg < 4; ++reg) {
        int m = mbase + reg;
        if (m < Mvalid) {
          out[(size_t)m * out_stride + n] = acc[i][j][reg] + bv;
        }
      }
    }
  }
}

// ---------------- recurrence (256 WGs x 1024 thr, split-K 4-way) ------------
// WGs 0..191: rec (verified split-K template). WGs 192..255: Wout cvt.
// Weight staging converts fp32->f16 inline.

struct RecArgs {
  const float *wh0, *wi1, *wh1;  // fp32 weights (converted in prologue)
  const float *gx0, *bh0, *bi1, *bh1;
  f16 *h0x, *h1x;  // fragment-major exchange buffers, [2][BB*HH] f16
  u16 *hs;
  u32 *bar;  // NWG flag lines, 64B each
  const float *wout;  // Wout fp32 (input)
  u16 *woutb;         // Wout bf16 (output, converted by WGs >= NWG)
};

__global__ __launch_bounds__(1024, 1) void rec_kernel(RecArgs ra) {
  __shared__ f16 wlds[48 * 1024];
  __shared__ float gh[4 * 48 * 33];
  const int tid = threadIdx.x;
  const int wg = blockIdx.x;

  if (wg >= NWG) {
    // ---- Wout converter WGs (idle CUs during rec) ----
    int i = (wg - NWG) * 1024 + tid;
    const int stride = (NWG_TOT - NWG) * 1024;
    for (; i < VV * HH / 4; i += stride) {
      float4 v = ((const float4*)ra.wout)[i];
      ushort4 o;
      o.x = f2bf(v.x); o.y = f2bf(v.y); o.z = f2bf(v.z); o.w = f2bf(v.w);
      ((ushort4*)ra.woutb)[i] = o;
    }
    return;
  }

  const int lane = tid & 63, wave = tid >> 6;
  const bool isL0 = wg < 64;
  const int Jbase = isL0 ? (wg * 16) : ((wg - 64) * 8);
  const int l15 = lane & 15;
  const int kg = lane >> 4;
  const int swz = (l15 & 7) << 4;
  const int kh = wave >> 2;   // K quarter 0..3
  const int khk = kh * 8;     // kk base
  float* ghk = gh + kh * (48 * 33);
  char* wb = (char*)wlds;

  // ---- prologue: stage this WG's weight slice into LDS, converting
  // fp32 -> f16 inline (same verified row mapping and XOR swizzle) ----
#pragma unroll
  for (int it = 0; it < 6; ++it) {
    int q = it * 1024 + tid;  // 0..6143
    int r = q >> 7;           // LDS row 0..47
    int c16 = q & 127;        // 16B f16 chunk (= 8 elems) within row
    const float* gp;
    if (isL0) {
      int gate = r >> 4, colr = r & 15;
      gp = ra.wh0 + ((size_t)(gate * HH + Jbase + colr)) * HH + c16 * 8;
    } else {
      int tile = r >> 3, colr = r & 7;
      int msrc = tile / 3, gate = tile - msrc * 3;
      const float* W = msrc ? ra.wh1 : ra.wi1;
      gp = W + ((size_t)(gate * HH + Jbase + colr)) * HH + c16 * 8;
    }
    float4 lo = ((const float4*)gp)[0];
    float4 hi = ((const float4*)gp)[1];
    f16x8 v = {(f16)lo.x, (f16)lo.y, (f16)lo.z, (f16)lo.w,
               (f16)hi.x, (f16)hi.y, (f16)hi.z, (f16)hi.w};
    int byte = r * 2048 + ((c16 * 16) ^ ((r & 7) << 4));
    *(f16x8*)(wb + byte) = v;
  }

  // ---- per-thread EW state (1 column each): biases + h_prev in registers --
  const int ewb = tid & 31, ewj = tid >> 5;  // L0: tid<512 (ewj 0..15); L1: tid<256
  float hprev = 0.f;
  float pb0r = 0.f, pb0z = 0.f, pb0n = 0.f;
  float pbrz_r = 0.f, pbrz_z = 0.f, pbn_i = 0.f, pbn_h = 0.f;
  if (isL0 && tid < 512) {
    int gj = Jbase + ewj;
    pb0r = ra.bh0[gj];
    pb0z = ra.bh0[HH + gj];
    pb0n = ra.bh0[2 * HH + gj];
  } else if (!isL0 && tid < 256) {
    int gj = Jbase + ewj;
    pbrz_r = ra.bi1[gj] + ra.bh1[gj];
    pbrz_z = ra.bi1[HH + gj] + ra.bh1[HH + gj];
    pbn_i = ra.bi1[2 * HH + gj];
    pbn_h = ra.bh1[2 * HH + gj];
  }
  __syncthreads();

  for (int p = 0; p < 64; ++p) {
    const int pb = p & 1, qb = (p + 1) & 1;
    if (isL0) {
      if (p < TT) {
        // prefetch gx for this thread's EW column
        float gr = 0.f, gz = 0.f, gn = 0.f;
        if (tid < 512) {
          const float* gxb = ra.gx0 + ((size_t)p * BB + ewb) * H3;
          int gj = Jbase + ewj;
          gr = gxb[gj];
          gz = gxb[HH + gj];
          gn = gxb[2 * HH + gj];
        }
        const int rt = (wave >> 1) & 1, tt = wave & 1;
        const f16* h0base = ra.h0x + (size_t)qb * (BB * HH);
        const int brow = rt * 16 + l15;
        f32x4 z = {0.f, 0.f, 0.f, 0.f};
        if (tt == 0) {
          f32x4 acc0 = z, acc1 = z;
#pragma unroll 4
          for (int ki = 0; ki < 8; ++ki) {
            int kk = khk + ki;
            f16x8 a = frag_ld(h0base, kk, kg, brow);
            int inner = (kk * 64 + kg * 16) ^ swz;
            f16x8 b0 = *(const f16x8*)(wb + (0 * 16 + l15) * 2048 + inner);
            f16x8 b1 = *(const f16x8*)(wb + (1 * 16 + l15) * 2048 + inner);
            acc0 = mfma_f16(a, b0, acc0);
            acc1 = mfma_f16(a, b1, acc1);
          }
#pragma unroll
          for (int r = 0; r < 4; ++r) {
            ghk[(l15)*33 + rt * 16 + kg * 4 + r] = acc0[r];
            ghk[(16 + l15) * 33 + rt * 16 + kg * 4 + r] = acc1[r];
          }
        } else {
          f32x4 acc2 = z;
#pragma unroll 4
          for (int ki = 0; ki < 8; ++ki) {
            int kk = khk + ki;
            f16x8 a = frag_ld(h0base, kk, kg, brow);
            int inner = (kk * 64 + kg * 16) ^ swz;
            f16x8 b2 = *(const f16x8*)(wb + (2 * 16 + l15) * 2048 + inner);
            acc2 = mfma_f16(a, b2, acc2);
          }
#pragma unroll
          for (int r = 0; r < 4; ++r)
            ghk[(32 + l15) * 33 + rt * 16 + kg * 4 + r] = acc2[r];
        }
        __syncthreads();
        // elementwise (1 col/thread, tid<512); pack (j,j+1) via lanes L,L+32
        if (tid < 512) {
          f16* hxc = ra.h0x + (size_t)pb * (BB * HH);
          float rh = pb0r, zh = pb0z, nh = pb0n;
#pragma unroll
          for (int g = 0; g < 4; ++g) {
            rh += gh[g * (48 * 33) + (ewj)*33 + ewb];
            zh += gh[g * (48 * 33) + (16 + ewj) * 33 + ewb];
            nh += gh[g * (48 * 33) + (32 + ewj) * 33 + ewb];
          }
          float r = sigm(gr + rh);
          float zz = sigm(gz + zh);
          float n = tanh_(gn + r * nh);
          float hn = (1.f - zz) * n + zz * hprev;
          hprev = hn;
          float other = __shfl_xor(hn, 32);
          if ((lane & 32) == 0) {
            union { f16 h[2]; u32 u; } pk;
            pk.h[0] = (f16)hn;
            pk.h[1] = (f16)other;
            ast32(frag_wslot(hxc, Jbase + ewj, ewb), pk.u);
          }
        }
      } else {
        __syncthreads();
      }
    } else {
      if (p >= 1) {
        const int rt = (wave >> 1) & 1, src = wave & 1;
        const f16* hbase = (src ? ra.h1x : ra.h0x) + (size_t)qb * (BB * HH);
        const int brow = rt * 16 + l15;
        const int rowb = src * 24 + (l15 & 7);
        f32x4 z = {0.f, 0.f, 0.f, 0.f};
        f32x4 acc0 = z, acc1 = z, acc2 = z;
#pragma unroll 4
        for (int ki = 0; ki < 8; ++ki) {
          int kk = khk + ki;
          f16x8 a = frag_ld(hbase, kk, kg, brow);
          int inner = (kk * 64 + kg * 16) ^ swz;
          f16x8 b0 = *(const f16x8*)(wb + (rowb + 0) * 2048 + inner);
          f16x8 b1 = *(const f16x8*)(wb + (rowb + 8) * 2048 + inner);
          f16x8 b2 = *(const f16x8*)(wb + (rowb + 16) * 2048 + inner);
          acc0 = mfma_f16(a, b0, acc0);
          acc1 = mfma_f16(a, b1, acc1);
          acc2 = mfma_f16(a, b2, acc2);
        }
        if (l15 < 8) {
          f32x4 accs[3] = {acc0, acc1, acc2};
#pragma unroll
          for (int g = 0; g < 3; ++g) {
            int cl = (src * 3 + g) * 8 + l15;
#pragma unroll
            for (int r = 0; r < 4; ++r)
              ghk[cl * 33 + rt * 16 + kg * 4 + r] = accs[g][r];
          }
        }
        __syncthreads();
        if (tid < 256) {
          f16* hxc = ra.h1x + (size_t)pb * (BB * HH);
          float gir = 0.f, giz = 0.f, gin = 0.f, ghr = 0.f, ghz = 0.f, ghn = 0.f;
#pragma unroll
          for (int g = 0; g < 4; ++g) {
            const float* gg = gh + g * (48 * 33);
            gir += gg[(ewj)*33 + ewb];
            giz += gg[(8 + ewj) * 33 + ewb];
            gin += gg[(16 + ewj) * 33 + ewb];
            ghr += gg[(24 + ewj) * 33 + ewb];
            ghz += gg[(32 + ewj) * 33 + ewb];
            ghn += gg[(40 + ewj) * 33 + ewb];
          }
          float r = sigm(gir + ghr + pbrz_r);
          float zz = sigm(giz + ghz + pbrz_z);
          float n = tanh_(gin + pbn_i + r * (ghn + pbn_h));
          float hn = (1.f - zz) * n + zz * hprev;
          hprev = hn;
          float other = __shfl_xor(hn, 32);
          if ((lane & 32) == 0) {
            union { f16 h[2]; u32 u; } pk;
            pk.h[0] = (f16)hn;
            pk.h[1] = (f16)other;
            ast32(frag_wslot(hxc, Jbase + ewj, ewb), pk.u);
            union { u16 h[2]; u32 u; } pb2;
            pb2.h[0] = f2bf(hn);
            pb2.h[1] = f2bf(other);
            *(u32*)&ra.hs[((size_t)(p - 1) * BB + ewb) * HH + Jbase + ewj] = pb2.u;
          }
        }
      } else {
        __syncthreads();
      }
    }
    if (p < 63) gbar(ra.bar, wg, (u32)(p + 1));
  }
}

// ---------------- final row reduction (over NT partials) + loss -------------

__global__ __launch_bounds__(256) void rowred2_kernel(const float* __restrict__ pmg,
                                                      const float* __restrict__ psg,
                                                      const float* __restrict__ logits,
                                                      const int* __restrict__ sent,
                                                      const int* __restrict__ length,
                                                      float* __restrict__ tok) {
  __shared__ float redm[4], reds[4];
  const int row = blockIdx.x;  // rr = b*63 + s
  const int b = row / TT, s = row % TT;
  const int tid = threadIdx.x;
  const int lane = tid & 63, wave = tid >> 6;

  float m = -1e30f, sum = 0.f;
  if (tid < NT) {
    m = pmg[(size_t)tid * MM + row];
    sum = psg[(size_t)tid * MM + row];
  }
  for (int off = 1; off < 64; off <<= 1) {
    float mo = __shfl_xor(m, off);
    float so = __shfl_xor(sum, off);
    float mn = fmaxf(m, mo);
    sum = sum * __expf(m - mn) + so * __expf(mo - mn);
    m = mn;
  }
  if (lane == 0) {
    redm[wave] = m;
    reds[wave] = sum;
  }
  __syncthreads();
  if (tid == 0) {
    float M = redm[0], S = reds[0];
#pragma unroll
    for (int w = 1; w < 4; ++w) {
      float mo = redm[w], so = reds[w];
      float mn = fmaxf(M, mo);
      S = S * __expf(M - mn) + so * __expf(mo - mn);
      M = mn;
    }
    float lse = M + __logf(S);
    int tgt = sent[b * SS + s + 1];
    float tl = logits[(size_t)row * VV + tgt] - lse;
    if (s >= length[b] - 1) tl = 0.f;
    tok[row] = tl;
  }
}

__global__ void loss_kernel(const float* __restrict__ tok, const int* __restrict__ length,
                            float* __restrict__ out0) {
  int lane = threadIdx.x;
  float v = 0.f;
  if (lane < BB) {
    float s = 0.f;
    for (int t = 0; t < TT; ++t) s += tok[lane * TT + t];
    float ln = (float)(length[lane] - 1);
    v = -s / ln;
  }
  v += __shfl_down(v, 16);
  v += __shfl_down(v, 8);
  v += __shfl_down(v, 4);
  v += __shfl_down(v, 2);
  v += __shfl_down(v, 1);
  if (lane == 0) out0[0] = v / (float)BB;
}

// ---------------- host ----------------

extern "C" void kernel_launch(void* const* d_in, const int* in_sizes, int n_in,
                              void* d_out, int out_size, void* d_ws, size_t ws_size,
                              hipStream_t stream) {
  const int* sent = (const int*)d_in[0];
  const int* length = (const int*)d_in[1];
  const float* emb = (const float*)d_in[2];
  const float* Wi0 = (const float*)d_in[3];
  const float* Wh0 = (const float*)d_in[4];
  const float* bi0 = (const float*)d_in[5];
  const float* bh0 = (const float*)d_in[6];
  const float* Wi1 = (const float*)d_in[7];
  const float* Wh1 = (const float*)d_in[8];
  const float* bi1 = (const float*)d_in[9];
  const float* bh1 = (const float*)d_in[10];
  const float* Wout = (const float*)d_in[11];
  const float* bout = (const float*)d_in[12];
  float* out = (float*)d_out;

  char* ws = (char*)d_ws;
  size_t off = 0;
  auto alloc = [&](size_t b) {
    char* p = ws + off;
    off = (off + b + 255) & ~(size_t)255;
    return p;
  };
  f16* wi0f = (f16*)alloc((size_t)H3 * EP * 2);
  f16* xf = (f16*)alloc((size_t)MP * EP * 2);
  float* gx0 = (float*)alloc((size_t)MM * H3 * 4);
  u16* woutb = (u16*)alloc((size_t)VV * HH * 2);  // converted inside rec
  u16* hs = (u16*)alloc((size_t)MP * HH * 2);
  f16* h0x = (f16*)alloc((size_t)2 * BB * HH * 2);
  f16* h1x = (f16*)alloc((size_t)2 * BB * HH * 2);
  float* tok = (float*)alloc((size_t)MM * 4);
  u32* bar = (u32*)alloc((size_t)NWG * 16 * 4);
  float* pmg = (float*)alloc((size_t)MM * NT * 4);
  float* psg = (float*)alloc((size_t)MM * NT * 4);

  hipMemsetAsync(h0x, 0, (size_t)2 * BB * HH * 2, stream);
  hipMemsetAsync(h1x, 0, (size_t)2 * BB * HH * 2, stream);
  hipMemsetAsync(hs, 0, (size_t)MP * HH * 2, stream);
  hipMemsetAsync(bar, 0, (size_t)NWG * 16 * 4, stream);
  hipMemsetAsync(xf + (size_t)MM * EP, 0, (size_t)(MP - MM) * EP * 2, stream);

  prep_front<<<1024, 256, 0, stream>>>(Wi0, wi0f, sent, emb, xf);

  gemm_bt_f16<<<16 * 24, 256, 0, stream>>>(xf, EP, wi0f, bi0, gx0, H3, 5, 16, MM);

  RecArgs ra{Wh0, Wi1, Wh1, gx0, bh0, bi1, bh1, h0x, h1x, hs, bar, Wout, woutb};
  void* kargs[] = {(void*)&ra};
  hipLaunchCooperativeKernel((void*)rec_kernel, dim3(NWG_TOT), dim3(1024), kargs, 0,
                             stream);

  gemm_bt<true, true><<<16 * 250, 256, 0, stream>>>(hs, HH, woutb, bout, out + 1, VV, 16,
                                                    16, MM, pmg, psg);

  rowred2_kernel<<<MM, 256, 0, stream>>>(pmg, psg, out + 1, sent, length, tok);
  loss_kernel<<<1, 64, 0, stream>>>(tok, length, out);
}